// Round 1
// baseline (1727.297 us; speedup 1.0000x reference)
//
#include <hip/hip_runtime.h>
#include <hip/hip_bf16.h>

// GraphSAGE 2-layer forward, fp32.
//   layer1: h   = sigmoid( (scatter_mean x) @ W1l + x @ W1r + b1 )   [N,64]
//   layer2: out =          (scatter_mean h) @ W2l + h @ W2r + b2     [N,40]
// edge_index[0]=src j, edge_index[1]=dst i (int32 on device).

#define N_FEAT 128
#define HID 64
#define NCLS 40

// ---------------------------------------------------------------------------
// Scatter: msg[dst] += feat[src], deg[dst] += 1 (atomics). One thread per
// (edge, 4-feature chunk); 16B vector load of the source row chunk.
// ---------------------------------------------------------------------------
template <int F>
__global__ void scatter_kernel(const float* __restrict__ feat,
                               const int* __restrict__ ei,
                               float* __restrict__ msg,
                               float* __restrict__ deg,
                               int ne) {
    constexpr int C = F / 4;
    int tid = blockIdx.x * blockDim.x + threadIdx.x;
    int e = tid / C;
    if (e >= ne) return;
    int c = tid - e * C;
    int s = ei[e];
    int d = ei[ne + e];
    float4 v = *(const float4*)&feat[(size_t)s * F + c * 4];
    float* p = &msg[(size_t)d * F + c * 4];
    unsafeAtomicAdd(p + 0, v.x);
    unsafeAtomicAdd(p + 1, v.y);
    unsafeAtomicAdd(p + 2, v.z);
    unsafeAtomicAdd(p + 3, v.w);
    if (deg != nullptr && c == 0) unsafeAtomicAdd(deg + d, 1.0f);
}

// ---------------------------------------------------------------------------
// Dense: out = (A1 * inv_deg) @ W1 + A2 @ W2 + bias, optional sigmoid.
// Block covers 128 nodes. NT = 64*(M/JT) threads: thread (ng = t&63,
// jg = t>>6) computes nodes {base+ng, base+64+ng} x outputs [jg*JT, +JT).
// A tile (128 x 32, stride 33: 2-way bank alias = free) and W tile
// (32 x M, read wave-uniform -> LDS broadcast) staged in LDS.
// ---------------------------------------------------------------------------
constexpr int KC = 32;

template <int K, int M, int JT, bool SIG, int NT>
__global__ __launch_bounds__(NT) void dense_kernel(
    const float* __restrict__ A1, const float* __restrict__ A2,
    const float* __restrict__ W1, const float* __restrict__ W2,
    const float* __restrict__ bias, const float* __restrict__ deg,
    float* __restrict__ out, int n) {
    __shared__ float At[128 * (KC + 1)];
    __shared__ __align__(16) float Wt[KC * M];
    __shared__ float inv_s[128];

    const int t = threadIdx.x;
    const int nodeBase = blockIdx.x * 128;
    const int ng = t & 63;
    const int jg = t >> 6;
    const int j0 = jg * JT;

    if (t < 128) {
        int node = nodeBase + t;
        float d = (node < n) ? deg[node] : 1.0f;
        inv_s[t] = 1.0f / fmaxf(d, 1.0f);
    }
    __syncthreads();

    float acc0[JT], acc1[JT];
#pragma unroll
    for (int i = 0; i < JT; ++i) {
        acc0[i] = 0.0f;
        acc1[i] = 0.0f;
    }

    for (int mat = 0; mat < 2; ++mat) {
        const float* __restrict__ A = mat ? A2 : A1;
        const float* __restrict__ W = mat ? W2 : W1;
        for (int cb = 0; cb < K; cb += KC) {
            // ---- stage A tile: 128 nodes x KC k (float4 global loads) ----
            for (int q = t; q < 128 * (KC / 4); q += NT) {
                int nl = q >> 3;  // KC/4 == 8 float4 per row
                int kq = q & 7;
                int node = nodeBase + nl;
                float4 v = make_float4(0.f, 0.f, 0.f, 0.f);
                if (node < n)
                    v = *(const float4*)&A[(size_t)node * K + cb + kq * 4];
                float sc = mat ? 1.0f : inv_s[nl];
                float* dst = &At[nl * (KC + 1) + kq * 4];
                dst[0] = v.x * sc;
                dst[1] = v.y * sc;
                dst[2] = v.z * sc;
                dst[3] = v.w * sc;
            }
            // ---- stage W tile: KC x M ----
            for (int q = t; q < KC * (M / 4); q += NT) {
                int kk = q / (M / 4);
                int jq = q - kk * (M / 4);
                *(float4*)&Wt[kk * M + jq * 4] =
                    *(const float4*)&W[(size_t)(cb + kk) * M + jq * 4];
            }
            __syncthreads();
#pragma unroll 4
            for (int kk = 0; kk < KC; ++kk) {
                float a0 = At[ng * (KC + 1) + kk];
                float a1 = At[(ng + 64) * (KC + 1) + kk];
#pragma unroll
                for (int jo = 0; jo < JT / 4; ++jo) {
                    float4 w = *(const float4*)&Wt[kk * M + j0 + jo * 4];
                    acc0[jo * 4 + 0] += a0 * w.x;
                    acc0[jo * 4 + 1] += a0 * w.y;
                    acc0[jo * 4 + 2] += a0 * w.z;
                    acc0[jo * 4 + 3] += a0 * w.w;
                    acc1[jo * 4 + 0] += a1 * w.x;
                    acc1[jo * 4 + 1] += a1 * w.y;
                    acc1[jo * 4 + 2] += a1 * w.z;
                    acc1[jo * 4 + 3] += a1 * w.w;
                }
            }
            __syncthreads();
        }
    }

    // ---- epilogue: + bias, optional sigmoid, float4 stores ----
    const int node0 = nodeBase + ng;
    const int node1 = nodeBase + 64 + ng;
#pragma unroll
    for (int jo = 0; jo < JT / 4; ++jo) {
        float4 b = *(const float4*)&bias[j0 + jo * 4];
        float4 v0, v1;
        v0.x = acc0[jo * 4 + 0] + b.x;
        v0.y = acc0[jo * 4 + 1] + b.y;
        v0.z = acc0[jo * 4 + 2] + b.z;
        v0.w = acc0[jo * 4 + 3] + b.w;
        v1.x = acc1[jo * 4 + 0] + b.x;
        v1.y = acc1[jo * 4 + 1] + b.y;
        v1.z = acc1[jo * 4 + 2] + b.z;
        v1.w = acc1[jo * 4 + 3] + b.w;
        if (SIG) {
            v0.x = 1.0f / (1.0f + __expf(-v0.x));
            v0.y = 1.0f / (1.0f + __expf(-v0.y));
            v0.z = 1.0f / (1.0f + __expf(-v0.z));
            v0.w = 1.0f / (1.0f + __expf(-v0.w));
            v1.x = 1.0f / (1.0f + __expf(-v1.x));
            v1.y = 1.0f / (1.0f + __expf(-v1.y));
            v1.z = 1.0f / (1.0f + __expf(-v1.z));
            v1.w = 1.0f / (1.0f + __expf(-v1.w));
        }
        if (node0 < n) *(float4*)&out[(size_t)node0 * M + j0 + jo * 4] = v0;
        if (node1 < n) *(float4*)&out[(size_t)node1 * M + j0 + jo * 4] = v1;
    }
}

extern "C" void kernel_launch(void* const* d_in, const int* in_sizes, int n_in,
                              void* d_out, int out_size, void* d_ws,
                              size_t ws_size, hipStream_t stream) {
    const float* x = (const float*)d_in[0];
    const int* ei = (const int*)d_in[1];
    const float* W1l = (const float*)d_in[2];
    const float* b1 = (const float*)d_in[3];
    const float* W1r = (const float*)d_in[4];
    const float* W2l = (const float*)d_in[5];
    const float* b2 = (const float*)d_in[6];
    const float* W2r = (const float*)d_in[7];
    float* out = (float*)d_out;

    const int n = in_sizes[0] / N_FEAT;   // 100000
    const int ne = in_sizes[1] / 2;       // 600000

    // workspace layout (floats): msg1[n*128] | deg[n] | h[n*64] | msg2[n*64]
    float* msg1 = (float*)d_ws;
    float* deg = msg1 + (size_t)n * N_FEAT;
    float* h = deg + n;
    float* msg2 = h + (size_t)n * HID;

    hipMemsetAsync(msg1, 0, (size_t)n * N_FEAT * sizeof(float), stream);
    hipMemsetAsync(deg, 0, (size_t)n * sizeof(float), stream);
    hipMemsetAsync(msg2, 0, (size_t)n * HID * sizeof(float), stream);

    // layer 1 scatter: x -> msg1 (+ degree count)
    {
        long long work = (long long)ne * (N_FEAT / 4);
        int blocks = (int)((work + 255) / 256);
        scatter_kernel<N_FEAT><<<blocks, 256, 0, stream>>>(x, ei, msg1, deg, ne);
    }
    // layer 1 dense: h = sigmoid(msg1*inv @ W1l + x @ W1r + b1)
    {
        int blocks = (n + 127) / 128;
        dense_kernel<N_FEAT, HID, 16, true, 256>
            <<<blocks, 256, 0, stream>>>(msg1, x, W1l, W1r, b1, deg, h, n);
    }
    // layer 2 scatter: h -> msg2
    {
        long long work = (long long)ne * (HID / 4);
        int blocks = (int)((work + 255) / 256);
        scatter_kernel<HID><<<blocks, 256, 0, stream>>>(h, ei, msg2, nullptr, ne);
    }
    // layer 2 dense: out = msg2*inv @ W2l + h @ W2r + b2
    {
        int blocks = (n + 127) / 128;
        dense_kernel<HID, NCLS, 8, false, 320>
            <<<blocks, 320, 0, stream>>>(msg2, h, W2l, W2r, b2, deg, out, n);
    }
}

// Round 2
// 358.960 us; speedup vs baseline: 4.8119x; 4.8119x over previous
//
#include <hip/hip_runtime.h>
#include <hip/hip_bf16.h>

// GraphSAGE 2-layer forward, fp32 — CSR-gather formulation.
//   zl = x@W1l, zr = x@W1r           (GEMM, fused dual-weight)
//   h  = sigmoid(csr_mean(zl) + zr + b1)
//   ql = h@W2l, qr = h@W2r
//   out = csr_mean(ql) + qr + b2
// CSR built on-device every call (histogram -> scan -> bucket fill).

#define N_FEAT 128
#define HID 64
#define NCLS 40

// ---------------------------------------------------------------------------
// CSR build
// ---------------------------------------------------------------------------
__global__ void hist_kernel(const int* __restrict__ ei, int* __restrict__ deg,
                            int ne) {
    int e = blockIdx.x * blockDim.x + threadIdx.x;
    if (e < ne) atomicAdd(&deg[ei[ne + e]], 1);
}

// block scans 2048 ints (256 thr x 8), writes inclusive prefix to off[i+1]
__global__ void scan_blocks(const int* __restrict__ deg, int* __restrict__ off,
                            int* __restrict__ bsums, int n) {
    __shared__ int lds[256];
    const int b = blockIdx.x, t = threadIdx.x;
    const int base = b * 2048 + t * 8;
    int v[8], s = 0;
#pragma unroll
    for (int i = 0; i < 8; ++i) {
        int idx = base + i;
        v[i] = (idx < n) ? deg[idx] : 0;
        s += v[i];
    }
    lds[t] = s;
    __syncthreads();
    for (int o = 1; o < 256; o <<= 1) {
        int y = (t >= o) ? lds[t - o] : 0;
        __syncthreads();
        lds[t] += y;
        __syncthreads();
    }
    int run = (t == 0) ? 0 : lds[t - 1];
#pragma unroll
    for (int i = 0; i < 8; ++i) {
        run += v[i];
        int idx = base + i;
        if (idx < n) off[idx + 1] = run;
    }
    if (t == 255) bsums[b] = lds[255];
    if (b == 0 && t == 0) off[0] = 0;
}

__global__ void scan_top(int* __restrict__ bsums, int nb) {
    if (threadIdx.x == 0) {
        int run = 0;
        for (int i = 0; i < nb; ++i) {
            int v = bsums[i];
            bsums[i] = run;
            run += v;
        }
    }
}

__global__ void scan_add(int* __restrict__ off, const int* __restrict__ bsums,
                         int n) {
    int i = blockIdx.x * blockDim.x + threadIdx.x;
    if (i < n) off[i + 1] += bsums[i >> 11];
}

__global__ void fill_csr(const int* __restrict__ ei, int* __restrict__ cursor,
                         int* __restrict__ csr, int ne) {
    int e = blockIdx.x * blockDim.x + threadIdx.x;
    if (e < ne) {
        int d = ei[ne + e];
        int p = atomicAdd(&cursor[d], 1);
        csr[p] = ei[e];
    }
}

// ---------------------------------------------------------------------------
// Dual-weight GEMM: Z[i, 0:MH] = A[i,:]@Wl, Z[i, MH:2MH] = A[i,:]@Wr.
// 128 nodes/block; thread (ng,jg) does 2 nodes x JT cols. A tile 128xKC
// (stride KC+1), W tile KCx2MH in LDS.
// ---------------------------------------------------------------------------
constexpr int KC = 32;

template <int K, int MH, int JT, int NT>
__global__ __launch_bounds__(NT) void gemm_dual(
    const float* __restrict__ A, const float* __restrict__ Wl,
    const float* __restrict__ Wr, float* __restrict__ Z, int n) {
    constexpr int M = 2 * MH;
    __shared__ float At[128 * (KC + 1)];
    __shared__ __align__(16) float Wt[KC * M];

    const int t = threadIdx.x;
    const int nodeBase = blockIdx.x * 128;
    const int ng = t & 63;
    const int jg = t >> 6;
    const int j0 = jg * JT;

    float acc0[JT], acc1[JT];
#pragma unroll
    for (int i = 0; i < JT; ++i) {
        acc0[i] = 0.0f;
        acc1[i] = 0.0f;
    }

    for (int cb = 0; cb < K; cb += KC) {
        // stage A tile (float4)
        for (int q = t; q < 128 * (KC / 4); q += NT) {
            int nl = q >> 3;
            int kq = q & 7;
            int node = nodeBase + nl;
            float4 v = make_float4(0.f, 0.f, 0.f, 0.f);
            if (node < n) v = *(const float4*)&A[(size_t)node * K + cb + kq * 4];
            float* dst = &At[nl * (KC + 1) + kq * 4];
            dst[0] = v.x; dst[1] = v.y; dst[2] = v.z; dst[3] = v.w;
        }
        // stage W tile: cols [0,MH) from Wl, [MH,2MH) from Wr
        for (int q = t; q < KC * (M / 4); q += NT) {
            int kk = q / (M / 4);
            int jq = q - kk * (M / 4);
            int j = jq * 4;
            const float* src = (j < MH) ? &Wl[(size_t)(cb + kk) * MH + j]
                                        : &Wr[(size_t)(cb + kk) * MH + (j - MH)];
            *(float4*)&Wt[kk * M + j] = *(const float4*)src;
        }
        __syncthreads();
#pragma unroll 4
        for (int kk = 0; kk < KC; ++kk) {
            float a0 = At[ng * (KC + 1) + kk];
            float a1 = At[(ng + 64) * (KC + 1) + kk];
#pragma unroll
            for (int jo = 0; jo < JT / 4; ++jo) {
                float4 w = *(const float4*)&Wt[kk * M + j0 + jo * 4];
                acc0[jo * 4 + 0] += a0 * w.x;
                acc0[jo * 4 + 1] += a0 * w.y;
                acc0[jo * 4 + 2] += a0 * w.z;
                acc0[jo * 4 + 3] += a0 * w.w;
                acc1[jo * 4 + 0] += a1 * w.x;
                acc1[jo * 4 + 1] += a1 * w.y;
                acc1[jo * 4 + 2] += a1 * w.z;
                acc1[jo * 4 + 3] += a1 * w.w;
            }
        }
        __syncthreads();
    }

    const int node0 = nodeBase + ng;
    const int node1 = nodeBase + 64 + ng;
#pragma unroll
    for (int jo = 0; jo < JT / 4; ++jo) {
        float4 v0 = make_float4(acc0[jo * 4 + 0], acc0[jo * 4 + 1],
                                acc0[jo * 4 + 2], acc0[jo * 4 + 3]);
        float4 v1 = make_float4(acc1[jo * 4 + 0], acc1[jo * 4 + 1],
                                acc1[jo * 4 + 2], acc1[jo * 4 + 3]);
        if (node0 < n) *(float4*)&Z[(size_t)node0 * M + j0 + jo * 4] = v0;
        if (node1 < n) *(float4*)&Z[(size_t)node1 * M + j0 + jo * 4] = v1;
    }
}

// ---------------------------------------------------------------------------
// CSR aggregate + epilogue: out[i] = act( mean_e Z[src_e, lane] + Z[i, F+lane]
//                                         + bias[lane] ).
// One wave per node, lane = feature. 2-way unrolled gather for ILP.
// ---------------------------------------------------------------------------
template <int F, int S, bool SIG>
__global__ void agg_kernel(const float* __restrict__ Z,
                           const int* __restrict__ off,
                           const int* __restrict__ csr,
                           const float* __restrict__ bias,
                           float* __restrict__ out, int n) {
    const int node = blockIdx.x * (blockDim.x >> 6) + (threadIdx.x >> 6);
    const int lane = threadIdx.x & 63;
    if (node >= n) return;
    const int start = off[node];
    const int end = off[node + 1];
    if (lane < F) {
        float acc0 = 0.f, acc1 = 0.f;
        int e = start;
        for (; e + 1 < end; e += 2) {
            int s0 = csr[e];
            int s1 = csr[e + 1];
            acc0 += Z[(size_t)s0 * S + lane];
            acc1 += Z[(size_t)s1 * S + lane];
        }
        if (e < end) acc0 += Z[(size_t)csr[e] * S + lane];
        float inv = 1.0f / fmaxf((float)(end - start), 1.0f);
        float r = (acc0 + acc1) * inv + Z[(size_t)node * S + F + lane] + bias[lane];
        if (SIG) r = 1.0f / (1.0f + __expf(-r));
        out[(size_t)node * F + lane] = r;
    }
}

// ---------------------------------------------------------------------------
extern "C" void kernel_launch(void* const* d_in, const int* in_sizes, int n_in,
                              void* d_out, int out_size, void* d_ws,
                              size_t ws_size, hipStream_t stream) {
    const float* x = (const float*)d_in[0];
    const int* ei = (const int*)d_in[1];
    const float* W1l = (const float*)d_in[2];
    const float* b1 = (const float*)d_in[3];
    const float* W1r = (const float*)d_in[4];
    const float* W2l = (const float*)d_in[5];
    const float* b2 = (const float*)d_in[6];
    const float* W2r = (const float*)d_in[7];
    float* out = (float*)d_out;

    const int n = in_sizes[0] / N_FEAT;  // 100000
    const int ne = in_sizes[1] / 2;      // 600000

    // ws layout: z [n*128] (reused as [n*80] for layer2) | h [n*64] | ints
    float* z = (float*)d_ws;
    float* h = z + (size_t)n * 128;
    int* deg = (int*)(h + (size_t)n * HID);
    int* off = deg + n;          // n+1
    int* cursor = off + (n + 1); // n+1
    int* csr = cursor + (n + 1); // ne
    int* bsums = csr + ne;       // scan partials

    const int nb = (n + 2047) / 2048;

    // ---- CSR build ----
    hipMemsetAsync(deg, 0, (size_t)n * sizeof(int), stream);
    hist_kernel<<<(ne + 255) / 256, 256, 0, stream>>>(ei, deg, ne);
    scan_blocks<<<nb, 256, 0, stream>>>(deg, off, bsums, n);
    scan_top<<<1, 64, 0, stream>>>(bsums, nb);
    scan_add<<<(n + 255) / 256, 256, 0, stream>>>(off, bsums, n);
    hipMemcpyAsync(cursor, off, (size_t)(n + 1) * sizeof(int),
                   hipMemcpyDeviceToDevice, stream);
    fill_csr<<<(ne + 255) / 256, 256, 0, stream>>>(ei, cursor, csr, ne);

    const int gblocks = (n + 127) / 128;
    const int ablocks = (n + 3) / 4;

    // ---- layer 1 ----
    gemm_dual<N_FEAT, HID, 16, 512>
        <<<gblocks, 512, 0, stream>>>(x, W1l, W1r, z, n);
    agg_kernel<HID, 2 * HID, true>
        <<<ablocks, 256, 0, stream>>>(z, off, csr, b1, h, n);

    // ---- layer 2 (z reused, stride 80) ----
    gemm_dual<HID, NCLS, 16, 320>
        <<<gblocks, 320, 0, stream>>>(h, W2l, W2r, z, n);
    agg_kernel<NCLS, 2 * NCLS, false>
        <<<ablocks, 256, 0, stream>>>(z, off, csr, b2, out, n);
}

// Round 3
// 304.651 us; speedup vs baseline: 5.6698x; 1.1783x over previous
//
#include <hip/hip_runtime.h>
#include <hip/hip_bf16.h>

// GraphSAGE 2-layer forward — CSR-gather + bf16 MFMA GEMMs.
//   zl|zr = x@[W1l|W1r]  (bf16 MFMA, z stored bf16 [n,128])
//   h  = sigmoid(csr_mean(zl) + zr + b1)        (h bf16 [n,64])
//   ql|qr = h@[W2l|W2r]  (bf16 MFMA, z reused [n,80])
//   out = csr_mean(ql) + qr + b2                (fp32 [n,40])

#define N_FEAT 128
#define HID 64
#define NCLS 40

typedef short short8 __attribute__((ext_vector_type(8)));
typedef float floatx4 __attribute__((ext_vector_type(4)));

static __device__ __forceinline__ short f2bf(float x) {
    __hip_bfloat16 h = __float2bfloat16(x);
    return __builtin_bit_cast(short, h);
}
static __device__ __forceinline__ float bf2f(unsigned short u) {
    unsigned int v = ((unsigned int)u) << 16;
    return __builtin_bit_cast(float, v);
}

// ---------------------------------------------------------------------------
// CSR build
// ---------------------------------------------------------------------------
__global__ void hist_kernel(const int* __restrict__ ei, int* __restrict__ deg,
                            int ne) {
    int e = blockIdx.x * blockDim.x + threadIdx.x;
    if (e < ne) atomicAdd(&deg[ei[ne + e]], 1);
}

__global__ void scan_blocks(const int* __restrict__ deg, int* __restrict__ off,
                            int* __restrict__ bsums, int n) {
    __shared__ int lds[256];
    const int b = blockIdx.x, t = threadIdx.x;
    const int base = b * 2048 + t * 8;
    int v[8], s = 0;
#pragma unroll
    for (int i = 0; i < 8; ++i) {
        int idx = base + i;
        v[i] = (idx < n) ? deg[idx] : 0;
        s += v[i];
    }
    lds[t] = s;
    __syncthreads();
    for (int o = 1; o < 256; o <<= 1) {
        int y = (t >= o) ? lds[t - o] : 0;
        __syncthreads();
        lds[t] += y;
        __syncthreads();
    }
    int run = (t == 0) ? 0 : lds[t - 1];
#pragma unroll
    for (int i = 0; i < 8; ++i) {
        run += v[i];
        int idx = base + i;
        if (idx < n) off[idx + 1] = run;
    }
    if (t == 255) bsums[b] = lds[255];
    if (b == 0 && t == 0) off[0] = 0;
}

__global__ void scan_top(int* __restrict__ bsums, int nb) {
    if (threadIdx.x == 0) {
        int run = 0;
        for (int i = 0; i < nb; ++i) {
            int v = bsums[i];
            bsums[i] = run;
            run += v;
        }
    }
}

__global__ void scan_add(int* __restrict__ off, const int* __restrict__ bsums,
                         int n) {
    int i = blockIdx.x * blockDim.x + threadIdx.x;
    if (i < n) off[i + 1] += bsums[i >> 11];
}

__global__ void fill_csr(const int* __restrict__ ei, int* __restrict__ cursor,
                         int* __restrict__ csr, int ne) {
    int e = blockIdx.x * blockDim.x + threadIdx.x;
    if (e < ne) {
        int d = ei[ne + e];
        int p = atomicAdd(&cursor[d], 1);
        csr[p] = ei[e];
    }
}

// ---------------------------------------------------------------------------
// Weight prep: transpose + cvt to bf16, concatenated [l|r] along n.
// Wt1[n=0..127][k=0..127], Wt2[n=0..79][k=0..63]  (row-major n-major).
// ---------------------------------------------------------------------------
__global__ void prep_w(const float* __restrict__ W1l, const float* __restrict__ W1r,
                       const float* __restrict__ W2l, const float* __restrict__ W2r,
                       unsigned short* __restrict__ wt1,
                       unsigned short* __restrict__ wt2) {
    int i = blockIdx.x * blockDim.x + threadIdx.x;
    if (i < 128 * 128) {
        int nn = i >> 7, k = i & 127;
        float v = (nn < 64) ? W1l[k * 64 + nn] : W1r[k * 64 + (nn - 64)];
        wt1[nn * 128 + k] = (unsigned short)f2bf(v);
    } else if (i < 128 * 128 + 80 * 64) {
        int j = i - 128 * 128;
        int nn = j >> 6, k = j & 63;
        float v = (nn < 40) ? W2l[k * 40 + nn] : W2r[k * 40 + (nn - 40)];
        wt2[nn * 64 + k] = (unsigned short)f2bf(v);
    }
}

// ---------------------------------------------------------------------------
// MFMA GEMM: Z[node, 0:M) = A[node,:] @ W (W pre-transposed bf16 [M][K]).
// Block = 256 thr (4 waves), 64 rows/block, wave w -> rows [16w,16w+16),
// all M/16 n-tiles. K staged fully in LDS (pad +8 bf16 for bank spread).
// A fp32 (inline cvt) or bf16 per AF32. Z out bf16.
// ---------------------------------------------------------------------------
template <int K, int M, bool AF32>
__global__ __launch_bounds__(256) void gemm_mfma(
    const void* __restrict__ Ain, const unsigned short* __restrict__ Wt,
    unsigned short* __restrict__ Z, int n) {
    constexpr int LDA = K + 8;
    constexpr int MT = M / 16;
    constexpr int KS = K / 32;
    constexpr int QROW = K / 8;  // 8-elem quanta per row
    __shared__ __align__(16) short At[64 * LDA];
    __shared__ __align__(16) short Bt[M * LDA];

    const int t = threadIdx.x;
    const int nodeBase = blockIdx.x * 64;

    // ---- stage A (64 x K) with optional fp32->bf16 cvt ----
    for (int q = t; q < 64 * QROW; q += 256) {
        int row = q / QROW;
        int k0 = (q % QROW) * 8;
        int node = nodeBase + row;
        short8 s = {0, 0, 0, 0, 0, 0, 0, 0};
        if (node < n) {
            if (AF32) {
                const float* A = (const float*)Ain + (size_t)node * K + k0;
                float4 v0 = *(const float4*)A;
                float4 v1 = *(const float4*)(A + 4);
                s[0] = f2bf(v0.x); s[1] = f2bf(v0.y);
                s[2] = f2bf(v0.z); s[3] = f2bf(v0.w);
                s[4] = f2bf(v1.x); s[5] = f2bf(v1.y);
                s[6] = f2bf(v1.z); s[7] = f2bf(v1.w);
            } else {
                s = *(const short8*)((const short*)Ain + (size_t)node * K + k0);
            }
        }
        *(short8*)&At[row * LDA + k0] = s;
    }
    // ---- stage W (M x K), already bf16 transposed ----
    for (int q = t; q < M * QROW; q += 256) {
        int row = q / QROW;
        int k0 = (q % QROW) * 8;
        *(short8*)&Bt[row * LDA + k0] =
            *(const short8*)((const short*)Wt + (size_t)row * K + k0);
    }
    __syncthreads();

    const int wave = t >> 6;
    const int lane = t & 63;
    const int m0 = wave * 16;
    const int fl = lane & 15;    // frag row (A) / col (B,D)
    const int quad = lane >> 4;  // frag k-group / D row-group

    floatx4 acc[MT];
#pragma unroll
    for (int nt = 0; nt < MT; ++nt) acc[nt] = (floatx4){0.f, 0.f, 0.f, 0.f};

#pragma unroll
    for (int ks = 0; ks < KS; ++ks) {
        const int kb = ks * 32 + quad * 8;
        short8 a = *(const short8*)&At[(m0 + fl) * LDA + kb];
#pragma unroll
        for (int nt = 0; nt < MT; ++nt) {
            short8 b = *(const short8*)&Bt[(nt * 16 + fl) * LDA + kb];
            acc[nt] = __builtin_amdgcn_mfma_f32_16x16x32_bf16(a, b, acc[nt], 0, 0, 0);
        }
    }

    // ---- epilogue: D[row=quad*4+r][col=fl] -> Z bf16 ----
#pragma unroll
    for (int nt = 0; nt < MT; ++nt) {
#pragma unroll
        for (int r = 0; r < 4; ++r) {
            int node = nodeBase + m0 + quad * 4 + r;
            if (node < n)
                Z[(size_t)node * M + nt * 16 + fl] = (unsigned short)f2bf(acc[nt][r]);
        }
    }
}

// ---------------------------------------------------------------------------
// CSR aggregate + epilogue. One wave per node, lane = feature (bf16 Z).
// out[i] = act( mean_e Z[src_e, lane] + Z[i, F+lane] + bias[lane] )
// ---------------------------------------------------------------------------
template <int F, int S, bool SIG, bool OUTBF>
__global__ void agg_kernel(const unsigned short* __restrict__ Z,
                           const int* __restrict__ off,
                           const int* __restrict__ csr,
                           const float* __restrict__ bias,
                           void* __restrict__ out, int n) {
    const int node = blockIdx.x * (blockDim.x >> 6) + (threadIdx.x >> 6);
    const int lane = threadIdx.x & 63;
    if (node >= n) return;
    const int start = off[node];
    const int end = off[node + 1];
    if (lane < F) {
        float acc0 = 0.f, acc1 = 0.f;
        int e = start;
        for (; e + 1 < end; e += 2) {
            int s0 = csr[e];
            int s1 = csr[e + 1];
            acc0 += bf2f(Z[(size_t)s0 * S + lane]);
            acc1 += bf2f(Z[(size_t)s1 * S + lane]);
        }
        if (e < end) acc0 += bf2f(Z[(size_t)csr[e] * S + lane]);
        float inv = 1.0f / fmaxf((float)(end - start), 1.0f);
        float r = (acc0 + acc1) * inv + bf2f(Z[(size_t)node * S + F + lane]) +
                  bias[lane];
        if (SIG) r = 1.0f / (1.0f + __expf(-r));
        if (OUTBF)
            ((unsigned short*)out)[(size_t)node * F + lane] = (unsigned short)f2bf(r);
        else
            ((float*)out)[(size_t)node * F + lane] = r;
    }
}

// ---------------------------------------------------------------------------
extern "C" void kernel_launch(void* const* d_in, const int* in_sizes, int n_in,
                              void* d_out, int out_size, void* d_ws,
                              size_t ws_size, hipStream_t stream) {
    const float* x = (const float*)d_in[0];
    const int* ei = (const int*)d_in[1];
    const float* W1l = (const float*)d_in[2];
    const float* b1 = (const float*)d_in[3];
    const float* W1r = (const float*)d_in[4];
    const float* W2l = (const float*)d_in[5];
    const float* b2 = (const float*)d_in[6];
    const float* W2r = (const float*)d_in[7];
    float* out = (float*)d_out;

    const int n = in_sizes[0] / N_FEAT;  // 100000
    const int ne = in_sizes[1] / 2;      // 600000

    // ws: z bf16 [n*128] | h bf16 [n*64] | wt1 [16384] | wt2 [5120] | ints
    unsigned short* z = (unsigned short*)d_ws;
    unsigned short* h = z + (size_t)n * 128;
    unsigned short* wt1 = h + (size_t)n * 64;
    unsigned short* wt2 = wt1 + 128 * 128;
    int* deg = (int*)(wt2 + 80 * 64);
    int* off = deg + n;
    int* cursor = off + (n + 1);
    int* csr = cursor + (n + 1);
    int* bsums = csr + ne;

    const int nb = (n + 2047) / 2048;

    // ---- CSR build + weight prep ----
    hipMemsetAsync(deg, 0, (size_t)n * sizeof(int), stream);
    prep_w<<<(128 * 128 + 80 * 64 + 255) / 256, 256, 0, stream>>>(
        W1l, W1r, W2l, W2r, wt1, wt2);
    hist_kernel<<<(ne + 255) / 256, 256, 0, stream>>>(ei, deg, ne);
    scan_blocks<<<nb, 256, 0, stream>>>(deg, off, bsums, n);
    scan_top<<<1, 64, 0, stream>>>(bsums, nb);
    scan_add<<<(n + 255) / 256, 256, 0, stream>>>(off, bsums, n);
    hipMemcpyAsync(cursor, off, (size_t)(n + 1) * sizeof(int),
                   hipMemcpyDeviceToDevice, stream);
    fill_csr<<<(ne + 255) / 256, 256, 0, stream>>>(ei, cursor, csr, ne);

    const int gblocks = (n + 63) / 64;
    const int ablocks = (n + 3) / 4;

    // ---- layer 1 ----
    gemm_mfma<N_FEAT, 128, true><<<gblocks, 256, 0, stream>>>(x, wt1, z, n);
    agg_kernel<HID, 128, true, true>
        <<<ablocks, 256, 0, stream>>>(z, off, csr, b1, h, n);

    // ---- layer 2 ----
    gemm_mfma<HID, 80, false><<<gblocks, 256, 0, stream>>>(h, wt2, z, n);
    agg_kernel<NCLS, 80, false, false>
        <<<ablocks, 256, 0, stream>>>(z, off, csr, b2, out, n);
}

// Round 4
// 261.407 us; speedup vs baseline: 6.6077x; 1.1654x over previous
//
#include <hip/hip_runtime.h>
#include <hip/hip_bf16.h>

// GraphSAGE 2-layer forward — CSR-gather + bf16 MFMA GEMMs.
//   zl|zr = x@[W1l|W1r]  (bf16 MFMA, z stored bf16 [n,128])
//   h  = sigmoid(csr_mean(zl) + zr + b1)        (h bf16 [n,64])
//   ql|qr = h@[W2l|W2r]  (bf16 MFMA, z reused [n,80])
//   out = csr_mean(ql) + qr + b2                (fp32 [n,40])
// agg kernels use batched gathers (8 edges issued together) for MLP.

#define N_FEAT 128
#define HID 64
#define NCLS 40

typedef short short8 __attribute__((ext_vector_type(8)));
typedef float floatx4 __attribute__((ext_vector_type(4)));

static __device__ __forceinline__ short f2bf(float x) {
    __hip_bfloat16 h = __float2bfloat16(x);
    return __builtin_bit_cast(short, h);
}
static __device__ __forceinline__ float bf2f(unsigned short u) {
    unsigned int v = ((unsigned int)u) << 16;
    return __builtin_bit_cast(float, v);
}

// ---------------------------------------------------------------------------
// CSR build
// ---------------------------------------------------------------------------
__global__ void hist_kernel(const int* __restrict__ ei, int* __restrict__ deg,
                            int ne) {
    int e = blockIdx.x * blockDim.x + threadIdx.x;
    if (e < ne) atomicAdd(&deg[ei[ne + e]], 1);
}

__global__ void scan_blocks(const int* __restrict__ deg, int* __restrict__ off,
                            int* __restrict__ bsums, int n) {
    __shared__ int lds[256];
    const int b = blockIdx.x, t = threadIdx.x;
    const int base = b * 2048 + t * 8;
    int v[8], s = 0;
#pragma unroll
    for (int i = 0; i < 8; ++i) {
        int idx = base + i;
        v[i] = (idx < n) ? deg[idx] : 0;
        s += v[i];
    }
    lds[t] = s;
    __syncthreads();
    for (int o = 1; o < 256; o <<= 1) {
        int y = (t >= o) ? lds[t - o] : 0;
        __syncthreads();
        lds[t] += y;
        __syncthreads();
    }
    int run = (t == 0) ? 0 : lds[t - 1];
#pragma unroll
    for (int i = 0; i < 8; ++i) {
        run += v[i];
        int idx = base + i;
        if (idx < n) off[idx + 1] = run;
    }
    if (t == 255) bsums[b] = lds[255];
    if (b == 0 && t == 0) off[0] = 0;
}

__global__ void scan_top(int* __restrict__ bsums, int nb) {
    if (threadIdx.x == 0) {
        int run = 0;
        for (int i = 0; i < nb; ++i) {
            int v = bsums[i];
            bsums[i] = run;
            run += v;
        }
    }
}

__global__ void scan_add(int* __restrict__ off, const int* __restrict__ bsums,
                         int n) {
    int i = blockIdx.x * blockDim.x + threadIdx.x;
    if (i < n) off[i + 1] += bsums[i >> 11];
}

__global__ void fill_csr(const int* __restrict__ ei, int* __restrict__ cursor,
                         int* __restrict__ csr, int ne) {
    int e = blockIdx.x * blockDim.x + threadIdx.x;
    if (e < ne) {
        int d = ei[ne + e];
        int p = atomicAdd(&cursor[d], 1);
        csr[p] = ei[e];
    }
}

// ---------------------------------------------------------------------------
// Weight prep: transpose + cvt to bf16, concatenated [l|r] along n.
// ---------------------------------------------------------------------------
__global__ void prep_w(const float* __restrict__ W1l, const float* __restrict__ W1r,
                       const float* __restrict__ W2l, const float* __restrict__ W2r,
                       unsigned short* __restrict__ wt1,
                       unsigned short* __restrict__ wt2) {
    int i = blockIdx.x * blockDim.x + threadIdx.x;
    if (i < 128 * 128) {
        int nn = i >> 7, k = i & 127;
        float v = (nn < 64) ? W1l[k * 64 + nn] : W1r[k * 64 + (nn - 64)];
        wt1[nn * 128 + k] = (unsigned short)f2bf(v);
    } else if (i < 128 * 128 + 80 * 64) {
        int j = i - 128 * 128;
        int nn = j >> 6, k = j & 63;
        float v = (nn < 40) ? W2l[k * 40 + nn] : W2r[k * 40 + (nn - 40)];
        wt2[nn * 64 + k] = (unsigned short)f2bf(v);
    }
}

// ---------------------------------------------------------------------------
// MFMA GEMM (unchanged from R3): Z[node,0:M) = A[node,:] @ Wt^T.
// ---------------------------------------------------------------------------
template <int K, int M, bool AF32>
__global__ __launch_bounds__(256) void gemm_mfma(
    const void* __restrict__ Ain, const unsigned short* __restrict__ Wt,
    unsigned short* __restrict__ Z, int n) {
    constexpr int LDA = K + 8;
    constexpr int MT = M / 16;
    constexpr int KS = K / 32;
    constexpr int QROW = K / 8;
    __shared__ __align__(16) short At[64 * LDA];
    __shared__ __align__(16) short Bt[M * LDA];

    const int t = threadIdx.x;
    const int nodeBase = blockIdx.x * 64;

    for (int q = t; q < 64 * QROW; q += 256) {
        int row = q / QROW;
        int k0 = (q % QROW) * 8;
        int node = nodeBase + row;
        short8 s = {0, 0, 0, 0, 0, 0, 0, 0};
        if (node < n) {
            if (AF32) {
                const float* A = (const float*)Ain + (size_t)node * K + k0;
                float4 v0 = *(const float4*)A;
                float4 v1 = *(const float4*)(A + 4);
                s[0] = f2bf(v0.x); s[1] = f2bf(v0.y);
                s[2] = f2bf(v0.z); s[3] = f2bf(v0.w);
                s[4] = f2bf(v1.x); s[5] = f2bf(v1.y);
                s[6] = f2bf(v1.z); s[7] = f2bf(v1.w);
            } else {
                s = *(const short8*)((const short*)Ain + (size_t)node * K + k0);
            }
        }
        *(short8*)&At[row * LDA + k0] = s;
    }
    for (int q = t; q < M * QROW; q += 256) {
        int row = q / QROW;
        int k0 = (q % QROW) * 8;
        *(short8*)&Bt[row * LDA + k0] =
            *(const short8*)((const short*)Wt + (size_t)row * K + k0);
    }
    __syncthreads();

    const int wave = t >> 6;
    const int lane = t & 63;
    const int m0 = wave * 16;
    const int fl = lane & 15;
    const int quad = lane >> 4;

    floatx4 acc[MT];
#pragma unroll
    for (int nt = 0; nt < MT; ++nt) acc[nt] = (floatx4){0.f, 0.f, 0.f, 0.f};

#pragma unroll
    for (int ks = 0; ks < KS; ++ks) {
        const int kb = ks * 32 + quad * 8;
        short8 a = *(const short8*)&At[(m0 + fl) * LDA + kb];
#pragma unroll
        for (int nt = 0; nt < MT; ++nt) {
            short8 b = *(const short8*)&Bt[(nt * 16 + fl) * LDA + kb];
            acc[nt] = __builtin_amdgcn_mfma_f32_16x16x32_bf16(a, b, acc[nt], 0, 0, 0);
        }
    }

#pragma unroll
    for (int nt = 0; nt < MT; ++nt) {
#pragma unroll
        for (int r = 0; r < 4; ++r) {
            int node = nodeBase + m0 + quad * 4 + r;
            if (node < n)
                Z[(size_t)node * M + nt * 16 + fl] = (unsigned short)f2bf(acc[nt][r]);
        }
    }
}

// ---------------------------------------------------------------------------
// CSR aggregate + epilogue, batched gathers. One wave per node, lane=feature.
// Per batch of 8 edges: scalar-load 8 csr indices (clamped for tail), issue
// all 8 row-gathers (independent -> 8 outstanding vmem), then accumulate
// with wave-uniform predication. MLP-limited, not chain-limited.
// ---------------------------------------------------------------------------
template <int F, int S, bool SIG, bool OUTBF>
__global__ void agg_kernel(const unsigned short* __restrict__ Z,
                           const int* __restrict__ off,
                           const int* __restrict__ csr,
                           const float* __restrict__ bias,
                           void* __restrict__ out, int n) {
    const int node = blockIdx.x * (blockDim.x >> 6) + (threadIdx.x >> 6);
    const int lane = threadIdx.x & 63;
    if (node >= n) return;
    const int start = off[node];
    const int end = off[node + 1];
    if (lane < F) {
        float acc = 0.f;
        for (int e = start; e < end; e += 8) {
            int idx[8];
            float v[8];
#pragma unroll
            for (int i = 0; i < 8; ++i) {
                int ee = (e + i < end) ? (e + i) : (end - 1);
                idx[i] = csr[ee];
            }
#pragma unroll
            for (int i = 0; i < 8; ++i)
                v[i] = bf2f(Z[(size_t)idx[i] * S + lane]);
#pragma unroll
            for (int i = 0; i < 8; ++i)
                acc += (e + i < end) ? v[i] : 0.f;
        }
        float inv = 1.0f / fmaxf((float)(end - start), 1.0f);
        float r = acc * inv + bf2f(Z[(size_t)node * S + F + lane]) + bias[lane];
        if (SIG) r = 1.0f / (1.0f + __expf(-r));
        if (OUTBF)
            ((unsigned short*)out)[(size_t)node * F + lane] = (unsigned short)f2bf(r);
        else
            ((float*)out)[(size_t)node * F + lane] = r;
    }
}

// ---------------------------------------------------------------------------
extern "C" void kernel_launch(void* const* d_in, const int* in_sizes, int n_in,
                              void* d_out, int out_size, void* d_ws,
                              size_t ws_size, hipStream_t stream) {
    const float* x = (const float*)d_in[0];
    const int* ei = (const int*)d_in[1];
    const float* W1l = (const float*)d_in[2];
    const float* b1 = (const float*)d_in[3];
    const float* W1r = (const float*)d_in[4];
    const float* W2l = (const float*)d_in[5];
    const float* b2 = (const float*)d_in[6];
    const float* W2r = (const float*)d_in[7];
    float* out = (float*)d_out;

    const int n = in_sizes[0] / N_FEAT;  // 100000
    const int ne = in_sizes[1] / 2;      // 600000

    // ws: z bf16 [n*128] | h bf16 [n*64] | wt1 | wt2 | ints
    unsigned short* z = (unsigned short*)d_ws;
    unsigned short* h = z + (size_t)n * 128;
    unsigned short* wt1 = h + (size_t)n * 64;
    unsigned short* wt2 = wt1 + 128 * 128;
    int* deg = (int*)(wt2 + 80 * 64);
    int* off = deg + n;
    int* cursor = off + (n + 1);
    int* csr = cursor + (n + 1);
    int* bsums = csr + ne;

    const int nb = (n + 2047) / 2048;

    // ---- CSR build + weight prep ----
    hipMemsetAsync(deg, 0, (size_t)n * sizeof(int), stream);
    prep_w<<<(128 * 128 + 80 * 64 + 255) / 256, 256, 0, stream>>>(
        W1l, W1r, W2l, W2r, wt1, wt2);
    hist_kernel<<<(ne + 255) / 256, 256, 0, stream>>>(ei, deg, ne);
    scan_blocks<<<nb, 256, 0, stream>>>(deg, off, bsums, n);
    scan_top<<<1, 64, 0, stream>>>(bsums, nb);
    scan_add<<<(n + 255) / 256, 256, 0, stream>>>(off, bsums, n);
    hipMemcpyAsync(cursor, off, (size_t)(n + 1) * sizeof(int),
                   hipMemcpyDeviceToDevice, stream);
    fill_csr<<<(ne + 255) / 256, 256, 0, stream>>>(ei, cursor, csr, ne);

    const int gblocks = (n + 63) / 64;
    const int ablocks = (n + 3) / 4;

    // ---- layer 1 ----
    gemm_mfma<N_FEAT, 128, true><<<gblocks, 256, 0, stream>>>(x, wt1, z, n);
    agg_kernel<HID, 128, true, true>
        <<<ablocks, 256, 0, stream>>>(z, off, csr, b1, h, n);

    // ---- layer 2 ----
    gemm_mfma<HID, 80, false><<<gblocks, 256, 0, stream>>>(h, wt2, z, n);
    agg_kernel<NCLS, 80, false, false>
        <<<ablocks, 256, 0, stream>>>(z, off, csr, b2, out, n);
}

// Round 5
// 255.683 us; speedup vs baseline: 6.7556x; 1.0224x over previous
//
#include <hip/hip_runtime.h>
#include <hip/hip_bf16.h>

// GraphSAGE 2-layer forward — CSR-gather + bf16 MFMA GEMMs.
//   zl = x@W1l, zr = x@W1r     (bf16 MFMA, SPLIT packed arrays [n,64])
//   h  = sigmoid(csr_mean(zl) + zr + b1)        (h bf16 [n,64])
//   ql = h@W2l, qr = h@W2r     (split packed [n,40])
//   out = csr_mean(ql) + qr + b2                (fp32 [n,40])
// Split zl/zr keeps the gather working set minimal (12.8 MB / 8 MB) for L2.

#define N_FEAT 128
#define HID 64
#define NCLS 40

typedef short short8 __attribute__((ext_vector_type(8)));
typedef float floatx4 __attribute__((ext_vector_type(4)));

static __device__ __forceinline__ short f2bf(float x) {
    __hip_bfloat16 h = __float2bfloat16(x);
    return __builtin_bit_cast(short, h);
}
static __device__ __forceinline__ float bf2f(unsigned short u) {
    unsigned int v = ((unsigned int)u) << 16;
    return __builtin_bit_cast(float, v);
}

// ---------------------------------------------------------------------------
// CSR build
// ---------------------------------------------------------------------------
__global__ void hist_kernel(const int* __restrict__ ei, int* __restrict__ deg,
                            int ne) {
    int e = blockIdx.x * blockDim.x + threadIdx.x;
    if (e < ne) atomicAdd(&deg[ei[ne + e]], 1);
}

__global__ void scan_blocks(const int* __restrict__ deg, int* __restrict__ off,
                            int* __restrict__ bsums, int n) {
    __shared__ int lds[256];
    const int b = blockIdx.x, t = threadIdx.x;
    const int base = b * 2048 + t * 8;
    int v[8], s = 0;
#pragma unroll
    for (int i = 0; i < 8; ++i) {
        int idx = base + i;
        v[i] = (idx < n) ? deg[idx] : 0;
        s += v[i];
    }
    lds[t] = s;
    __syncthreads();
    for (int o = 1; o < 256; o <<= 1) {
        int y = (t >= o) ? lds[t - o] : 0;
        __syncthreads();
        lds[t] += y;
        __syncthreads();
    }
    int run = (t == 0) ? 0 : lds[t - 1];
#pragma unroll
    for (int i = 0; i < 8; ++i) {
        run += v[i];
        int idx = base + i;
        if (idx < n) off[idx + 1] = run;
    }
    if (t == 255) bsums[b] = lds[255];
    if (b == 0 && t == 0) off[0] = 0;
}

// parallel exclusive scan of block sums (nb <= 256)
__global__ void scan_top(int* __restrict__ bsums, int nb) {
    __shared__ int lds[256];
    const int t = threadIdx.x;
    lds[t] = (t < nb) ? bsums[t] : 0;
    __syncthreads();
    for (int o = 1; o < 256; o <<= 1) {
        int y = (t >= o) ? lds[t - o] : 0;
        __syncthreads();
        lds[t] += y;
        __syncthreads();
    }
    if (t < nb) bsums[t] = (t == 0) ? 0 : lds[t - 1];
}

// add block prefixes; also materialize cursor = off (replaces d2d memcpy)
__global__ void scan_add(int* __restrict__ off, int* __restrict__ cursor,
                         const int* __restrict__ bsums, int n) {
    int i = blockIdx.x * blockDim.x + threadIdx.x;
    if (i < n) {
        int v = off[i + 1] + bsums[i >> 11];
        off[i + 1] = v;
        cursor[i + 1] = v;
    }
    if (i == 0) cursor[0] = 0;
}

__global__ void fill_csr(const int* __restrict__ ei, int* __restrict__ cursor,
                         int* __restrict__ csr, int ne) {
    int e = blockIdx.x * blockDim.x + threadIdx.x;
    if (e < ne) {
        int d = ei[ne + e];
        int p = atomicAdd(&cursor[d], 1);
        csr[p] = ei[e];
    }
}

// ---------------------------------------------------------------------------
// Weight prep: transpose + cvt to bf16, concatenated [l|r] along n.
// wt1[n=0..127][k=0..127], wt2[n=0..79][k=0..63]
// ---------------------------------------------------------------------------
__global__ void prep_w(const float* __restrict__ W1l, const float* __restrict__ W1r,
                       const float* __restrict__ W2l, const float* __restrict__ W2r,
                       unsigned short* __restrict__ wt1,
                       unsigned short* __restrict__ wt2) {
    int i = blockIdx.x * blockDim.x + threadIdx.x;
    if (i < 128 * 128) {
        int nn = i >> 7, k = i & 127;
        float v = (nn < 64) ? W1l[k * 64 + nn] : W1r[k * 64 + (nn - 64)];
        wt1[nn * 128 + k] = (unsigned short)f2bf(v);
    } else if (i < 128 * 128 + 80 * 64) {
        int j = i - 128 * 128;
        int nn = j >> 6, k = j & 63;
        float v = (nn < 40) ? W2l[k * 40 + nn] : W2r[k * 40 + (nn - 40)];
        wt2[nn * 64 + k] = (unsigned short)f2bf(v);
    }
}

// ---------------------------------------------------------------------------
// MFMA GEMM: cols [0,MH) -> Zl packed [n,MH], cols [MH,2MH) -> Zr [n,MH].
// Block = 256 thr (4 waves), 64 rows/block; K fully staged in LDS (+8 pad).
// ---------------------------------------------------------------------------
template <int K, int MH, bool AF32>
__global__ __launch_bounds__(256) void gemm_mfma(
    const void* __restrict__ Ain, const unsigned short* __restrict__ Wt,
    unsigned short* __restrict__ Zl, unsigned short* __restrict__ Zr, int n) {
    constexpr int M = 2 * MH;
    constexpr int LDA = K + 8;
    constexpr int MT = (M + 15) / 16;
    constexpr int KS = K / 32;
    constexpr int QROW = K / 8;
    __shared__ __align__(16) short At[64 * LDA];
    __shared__ __align__(16) short Bt[M * LDA];

    const int t = threadIdx.x;
    const int nodeBase = blockIdx.x * 64;

    for (int q = t; q < 64 * QROW; q += 256) {
        int row = q / QROW;
        int k0 = (q % QROW) * 8;
        int node = nodeBase + row;
        short8 s = {0, 0, 0, 0, 0, 0, 0, 0};
        if (node < n) {
            if (AF32) {
                const float* A = (const float*)Ain + (size_t)node * K + k0;
                float4 v0 = *(const float4*)A;
                float4 v1 = *(const float4*)(A + 4);
                s[0] = f2bf(v0.x); s[1] = f2bf(v0.y);
                s[2] = f2bf(v0.z); s[3] = f2bf(v0.w);
                s[4] = f2bf(v1.x); s[5] = f2bf(v1.y);
                s[6] = f2bf(v1.z); s[7] = f2bf(v1.w);
            } else {
                s = *(const short8*)((const short*)Ain + (size_t)node * K + k0);
            }
        }
        *(short8*)&At[row * LDA + k0] = s;
    }
    for (int q = t; q < M * QROW; q += 256) {
        int row = q / QROW;
        int k0 = (q % QROW) * 8;
        *(short8*)&Bt[row * LDA + k0] =
            *(const short8*)((const short*)Wt + (size_t)row * K + k0);
    }
    __syncthreads();

    const int wave = t >> 6;
    const int lane = t & 63;
    const int m0 = wave * 16;
    const int fl = lane & 15;
    const int quad = lane >> 4;

    floatx4 acc[MT];
#pragma unroll
    for (int nt = 0; nt < MT; ++nt) acc[nt] = (floatx4){0.f, 0.f, 0.f, 0.f};

#pragma unroll
    for (int ks = 0; ks < KS; ++ks) {
        const int kb = ks * 32 + quad * 8;
        short8 a = *(const short8*)&At[(m0 + fl) * LDA + kb];
#pragma unroll
        for (int nt = 0; nt < MT; ++nt) {
            short8 b = *(const short8*)&Bt[(nt * 16 + fl) * LDA + kb];
            acc[nt] = __builtin_amdgcn_mfma_f32_16x16x32_bf16(a, b, acc[nt], 0, 0, 0);
        }
    }

    // epilogue: D[row=quad*4+r][col=nt*16+fl] -> split Zl/Zr (packed MH)
#pragma unroll
    for (int nt = 0; nt < MT; ++nt) {
        const int col = nt * 16 + fl;
#pragma unroll
        for (int r = 0; r < 4; ++r) {
            int node = nodeBase + m0 + quad * 4 + r;
            if (node < n) {
                unsigned short v = (unsigned short)f2bf(acc[nt][r]);
                if (col < MH)
                    Zl[(size_t)node * MH + col] = v;
                else
                    Zr[(size_t)node * MH + (col - MH)] = v;
            }
        }
    }
}

// ---------------------------------------------------------------------------
// CSR aggregate + epilogue, batched gathers (8 edges in flight). One wave
// per node, lane = feature. Zl/Zr packed with stride F.
// ---------------------------------------------------------------------------
template <int F, bool SIG, bool OUTBF>
__global__ void agg_kernel(const unsigned short* __restrict__ Zl,
                           const unsigned short* __restrict__ Zr,
                           const int* __restrict__ off,
                           const int* __restrict__ csr,
                           const float* __restrict__ bias,
                           void* __restrict__ out, int n) {
    const int node = blockIdx.x * (blockDim.x >> 6) + (threadIdx.x >> 6);
    const int lane = threadIdx.x & 63;
    if (node >= n) return;
    const int start = off[node];
    const int end = off[node + 1];
    if (lane < F) {
        float acc = 0.f;
        for (int e = start; e < end; e += 8) {
            int idx[8];
            float v[8];
#pragma unroll
            for (int i = 0; i < 8; ++i) {
                int ee = (e + i < end) ? (e + i) : (end - 1);
                idx[i] = csr[ee];
            }
#pragma unroll
            for (int i = 0; i < 8; ++i)
                v[i] = bf2f(Zl[(size_t)idx[i] * F + lane]);
#pragma unroll
            for (int i = 0; i < 8; ++i)
                acc += (e + i < end) ? v[i] : 0.f;
        }
        float inv = 1.0f / fmaxf((float)(end - start), 1.0f);
        float r = acc * inv + bf2f(Zr[(size_t)node * F + lane]) + bias[lane];
        if (SIG) r = 1.0f / (1.0f + __expf(-r));
        if (OUTBF)
            ((unsigned short*)out)[(size_t)node * F + lane] = (unsigned short)f2bf(r);
        else
            ((float*)out)[(size_t)node * F + lane] = r;
    }
}

// ---------------------------------------------------------------------------
extern "C" void kernel_launch(void* const* d_in, const int* in_sizes, int n_in,
                              void* d_out, int out_size, void* d_ws,
                              size_t ws_size, hipStream_t stream) {
    const float* x = (const float*)d_in[0];
    const int* ei = (const int*)d_in[1];
    const float* W1l = (const float*)d_in[2];
    const float* b1 = (const float*)d_in[3];
    const float* W1r = (const float*)d_in[4];
    const float* W2l = (const float*)d_in[5];
    const float* b2 = (const float*)d_in[6];
    const float* W2r = (const float*)d_in[7];
    float* out = (float*)d_out;

    const int n = in_sizes[0] / N_FEAT;  // 100000
    const int ne = in_sizes[1] / 2;      // 600000

    // ws: zl1|zr1 [n*64] | h [n*64] | zl2|zr2 [n*40] | wt1 | wt2 | ints
    unsigned short* zl1 = (unsigned short*)d_ws;
    unsigned short* zr1 = zl1 + (size_t)n * HID;
    unsigned short* h = zr1 + (size_t)n * HID;
    unsigned short* zl2 = h + (size_t)n * HID;
    unsigned short* zr2 = zl2 + (size_t)n * NCLS;
    unsigned short* wt1 = zr2 + (size_t)n * NCLS;
    unsigned short* wt2 = wt1 + 128 * 128;
    int* deg = (int*)(wt2 + 80 * 64);
    int* off = deg + n;
    int* cursor = off + (n + 1);
    int* csr = cursor + (n + 1);
    int* bsums = csr + ne;

    const int nb = (n + 2047) / 2048;

    // ---- CSR build + weight prep ----
    hipMemsetAsync(deg, 0, (size_t)n * sizeof(int), stream);
    prep_w<<<(128 * 128 + 80 * 64 + 255) / 256, 256, 0, stream>>>(
        W1l, W1r, W2l, W2r, wt1, wt2);
    hist_kernel<<<(ne + 255) / 256, 256, 0, stream>>>(ei, deg, ne);
    scan_blocks<<<nb, 256, 0, stream>>>(deg, off, bsums, n);
    scan_top<<<1, 256, 0, stream>>>(bsums, nb);
    scan_add<<<(n + 255) / 256, 256, 0, stream>>>(off, cursor, bsums, n);
    fill_csr<<<(ne + 255) / 256, 256, 0, stream>>>(ei, cursor, csr, ne);

    const int gblocks = (n + 63) / 64;
    const int ablocks = (n + 3) / 4;

    // ---- layer 1 ----
    gemm_mfma<N_FEAT, HID, true><<<gblocks, 256, 0, stream>>>(x, wt1, zl1, zr1, n);
    agg_kernel<HID, true, true>
        <<<ablocks, 256, 0, stream>>>(zl1, zr1, off, csr, b1, h, n);

    // ---- layer 2 ----
    gemm_mfma<HID, NCLS, false><<<gblocks, 256, 0, stream>>>(h, wt2, zl2, zr2, n);
    agg_kernel<NCLS, false, false>
        <<<ablocks, 256, 0, stream>>>(zl2, zr2, off, csr, b2, out, n);
}